// Round 6
// baseline (260.560 us; speedup 1.0000x reference)
//
#include <hip/hip_runtime.h>
#include <hip/hip_bf16.h>
#include <stdint.h>

// Problem constants: B=4, S=2048, D=1024, H=16, HD=64
#define B_  4
#define S_  2048
#define D_  1024
#define H_  16
#define HD_ 64

typedef __attribute__((ext_vector_type(8))) short          s16x8;   // MFMA A/B frag (8 bf16)
typedef __attribute__((ext_vector_type(4))) float          f32x4;   // MFMA C/D frag
typedef __attribute__((ext_vector_type(8))) unsigned short u16x8;   // 16B bf16 chunk

__device__ __forceinline__ unsigned short f2bf(float f) {
  union { float f; unsigned int u; } v; v.f = f;
  unsigned int u = v.u;
  u += 0x7fffu + ((u >> 16) & 1u);       // RNE
  return (unsigned short)(u >> 16);
}

// async global->LDS, 16B per lane; LDS dest = wave-uniform base + lane*16
#define GLDS16(g, l)                                                           \
  __builtin_amdgcn_global_load_lds(                                            \
      (const __attribute__((address_space(1))) void*)(g),                      \
      (__attribute__((address_space(3))) void*)(l), 16, 0, 0)

// ---------------------------------------------------------------- converts
__global__ void k_cvt(const float* __restrict__ src, unsigned short* __restrict__ dst, int n4) {
  int i = blockIdx.x * blockDim.x + threadIdx.x;
  int stride = gridDim.x * blockDim.x;
  for (int j = i; j < n4; j += stride) {
    float4 v = reinterpret_cast<const float4*>(src)[j];
    ushort4 o;
    o.x = f2bf(v.x); o.y = f2bf(v.y); o.z = f2bf(v.z); o.w = f2bf(v.w);
    reinterpret_cast<ushort4*>(dst)[j] = o;
  }
}

// fp32 [R][C] -> bf16 [C][R]   (weights -> B^T layout for gemm-BT)
__global__ void k_tpose_cvt(const float* __restrict__ src, unsigned short* __restrict__ dst,
                            int R, int C) {
  __shared__ unsigned short tile[64][72];
  int c0 = blockIdx.x * 64, r0 = blockIdx.y * 64;
  int tx = threadIdx.x & 63, ty = threadIdx.x >> 6;
#pragma unroll
  for (int i = 0; i < 16; ++i) {
    int r = ty * 16 + i;
    tile[r][tx] = f2bf(src[(size_t)(r0 + r) * C + c0 + tx]);
  }
  __syncthreads();
#pragma unroll
  for (int i = 0; i < 16; ++i) {
    int c = ty * 16 + i;
    dst[(size_t)(c0 + c) * R + r0 + tx] = tile[tx][c];
  }
}

// bf16 V [BH][S][HD] -> Vt [BH][HD][S]
__global__ void k_tpose_v(const unsigned short* __restrict__ src, unsigned short* __restrict__ dst) {
  __shared__ unsigned short tile[64][72];
  int s0 = blockIdx.x * 64, bh = blockIdx.y;
  int tx = threadIdx.x & 63, ty = threadIdx.x >> 6;
  const unsigned short* sb = src + (size_t)bh * S_ * HD_;
  unsigned short*       db = dst + (size_t)bh * S_ * HD_;
#pragma unroll
  for (int i = 0; i < 16; ++i) {
    int r = ty * 16 + i;
    tile[r][tx] = sb[(size_t)(s0 + r) * HD_ + tx];
  }
  __syncthreads();
#pragma unroll
  for (int i = 0; i < 16; ++i) {
    int hd = ty * 16 + i;
    db[(size_t)hd * S_ + s0 + tx] = tile[tx][hd];
  }
}

// ---------------------------------------------------------------- GEMM core
// C[128x128] = A[M,K] @ Bt[N,K]^T ; bf16 in, f32 acc; 4 waves (2x2), wave
// tile 64x64 = 4x4 frags of mfma_f32_16x16x32_bf16.
// Staging: global_load_lds width=16, LINEAR LDS dest (m104 rule), XOR chunk
// swizzle applied to the GLOBAL source address (same involution the reads
// use). One barrier per K-step.
__device__ __forceinline__ void gemm_core(const unsigned short* __restrict__ A,
                                          const unsigned short* __restrict__ Bt,
                                          int K, int m0, int n0,
                                          unsigned short* sm, f32x4 acc[4][4]) {
  const int t = threadIdx.x;
  const int w = t >> 6, l = t & 63;
  const int wm = w >> 1, wn = w & 1;
  const int lo = l & 15, hi = l >> 4;

  // chunk ci = j*256 + w*64 + l  (j=0,1); row = ci>>2; source chunk pre-swizzled
  const int ci0 = w * 64 + l, ci1 = ci0 + 256;
  const int rA0 = ci0 >> 2, cA0 = (ci0 & 3) ^ ((rA0 >> 1) & 3);
  const int rA1 = ci1 >> 2, cA1 = (ci1 & 3) ^ ((rA1 >> 1) & 3);
  const unsigned short* gA0 = A  + (size_t)(m0 + rA0) * K + cA0 * 8;
  const unsigned short* gA1 = A  + (size_t)(m0 + rA1) * K + cA1 * 8;
  const unsigned short* gB0 = Bt + (size_t)(n0 + rA0) * K + cA0 * 8;
  const unsigned short* gB1 = Bt + (size_t)(n0 + rA1) * K + cA1 * 8;
  const int ldsA0 = (w * 64) * 8;          // wave-uniform LDS bases (shorts)
  const int ldsA1 = (256 + w * 64) * 8;

#pragma unroll
  for (int m = 0; m < 4; ++m)
#pragma unroll
    for (int n = 0; n < 4; ++n)
      acc[m][n] = (f32x4){0.f, 0.f, 0.f, 0.f};

  const int NT = K >> 5;  // BK = 32

  // prologue: tile 0 -> buf 0
  {
    unsigned short* b = sm;
    GLDS16(gA0, b + ldsA0);
    GLDS16(gA1, b + ldsA1);
    GLDS16(gB0, b + 4096 + ldsA0);
    GLDS16(gB1, b + 4096 + ldsA1);
  }

  for (int kt = 0; kt < NT; ++kt) {
    __syncthreads();   // vmcnt(0)+lgkmcnt(0) drain: buf[kt&1] staged, prev reads done
    if (kt + 1 < NT) {                       // issue next tile into other buffer
      unsigned short* b = sm + ((kt + 1) & 1) * 8192;
      const int ko = (kt + 1) << 5;
      GLDS16(gA0 + ko, b + ldsA0);
      GLDS16(gA1 + ko, b + ldsA1);
      GLDS16(gB0 + ko, b + 4096 + ldsA0);
      GLDS16(gB1 + ko, b + 4096 + ldsA1);
    }
    const unsigned short* Ab = sm + (kt & 1) * 8192;
    const unsigned short* Bb = Ab + 4096;
    s16x8 af[4], bfr[4];
#pragma unroll
    for (int m = 0; m < 4; ++m) {
      int row = wm * 64 + m * 16 + lo;
      af[m] = *(const s16x8*)(Ab + row * 32 + ((hi ^ ((row >> 1) & 3)) << 3));
    }
#pragma unroll
    for (int n = 0; n < 4; ++n) {
      int row = wn * 64 + n * 16 + lo;
      bfr[n] = *(const s16x8*)(Bb + row * 32 + ((hi ^ ((row >> 1) & 3)) << 3));
    }
    __builtin_amdgcn_s_setprio(1);
#pragma unroll
    for (int m = 0; m < 4; ++m)
#pragma unroll
      for (int n = 0; n < 4; ++n)
        acc[m][n] = __builtin_amdgcn_mfma_f32_16x16x32_bf16(af[m], bfr[n], acc[m][n], 0, 0, 0);
    __builtin_amdgcn_s_setprio(0);
  }
}

// GEMM1: qkv = x @ W_attn + b ; scatter into Q/K/V [B,H,S,HD] bf16.
// Q is pre-scaled by 0.125*log2(e) so attention runs in exp2 domain.
__global__ __launch_bounds__(256, 3)
void k_gemm_qkv(const unsigned short* __restrict__ A, const unsigned short* __restrict__ Bt,
                const float* __restrict__ bias,
                unsigned short* __restrict__ Qh, unsigned short* __restrict__ Kh,
                unsigned short* __restrict__ Vh) {
  __shared__ unsigned short sm[2 * 8192];
  const int m0 = blockIdx.y * 128, n0 = blockIdx.x * 128;
  f32x4 acc[4][4];
  gemm_core(A, Bt, 1024, m0, n0, sm, acc);
  const int t = threadIdx.x, w = t >> 6, l = t & 63;
  const int wm = w >> 1, wn = w & 1, lo = l & 15, hi = l >> 4;
#pragma unroll
  for (int m = 0; m < 4; ++m)
#pragma unroll
    for (int n = 0; n < 4; ++n) {
      int col = n0 + wn * 64 + n * 16 + lo;           // 0..3071
      float bv = bias[col];
      int sel = col >> 10, cw = col & 1023, h = cw >> 6, hd = cw & 63;
      float scl = (sel == 0) ? 0.18033688011112042f : 1.0f;  // log2(e)/8
      unsigned short* dst = (sel == 0) ? Qh : ((sel == 1) ? Kh : Vh);
#pragma unroll
      for (int r = 0; r < 4; ++r) {
        int row = m0 + wm * 64 + m * 16 + hi * 4 + r;
        int b = row >> 11, s = row & 2047;
        dst[(((size_t)b * H_ + h) * S_ + s) * HD_ + hd] = f2bf((acc[m][n][r] + bv) * scl);
      }
    }
}

// GEMM2: out = ctx @ W_proj + b ; fp32 out
__global__ __launch_bounds__(256, 3)
void k_gemm_proj(const unsigned short* __restrict__ A, const unsigned short* __restrict__ Bt,
                 const float* __restrict__ bias, float* __restrict__ C, int N) {
  __shared__ unsigned short sm[2 * 8192];
  const int m0 = blockIdx.y * 128, n0 = blockIdx.x * 128;
  f32x4 acc[4][4];
  gemm_core(A, Bt, 1024, m0, n0, sm, acc);
  const int t = threadIdx.x, w = t >> 6, l = t & 63;
  const int wm = w >> 1, wn = w & 1, lo = l & 15, hi = l >> 4;
#pragma unroll
  for (int m = 0; m < 4; ++m)
#pragma unroll
    for (int n = 0; n < 4; ++n) {
      int col = n0 + wn * 64 + n * 16 + lo;
      float bv = bias[col];
#pragma unroll
      for (int r = 0; r < 4; ++r) {
        int row = m0 + wm * 64 + m * 16 + hi * 4 + r;
        C[(size_t)row * N + col] = acc[m][n][r] + bv;
      }
    }
}

// ---------------------------------------------------------------- attention
// Swapped QK^T (mfma(K,Q)); K rows LDS-permuted so the PV A-fragment is
// lane-resident after cvt_pk (zero shuffles for P); G4 XOR chunk swizzle on
// K/V (0 bank conflicts, round-3 verified). T13 defer-max (THR=8, exp2).
// Round-6 structure (fix for round 4/5 barrier-bound fusion):
//  - 256-thread blocks, one q-tile each, 1024 blocks -> ~4 blocks/CU
//    co-resident; imbalance absorbed by dynamic refill.
//  - double-buffered K/V LDS + T14 async-STAGE split: issue global loads
//    BEFORE compute, ds_write into other buffer AFTER compute -> ONE
//    barrier per KV tile (was 2) and HBM latency hidden under compute.
//  - XCD swizzle: bid%8 = XCD; all 16 q-tiles of a bh on one XCD ->
//    per-XCD K/V working set 8 bh x 512KB = 4MB = L2-resident.
__global__ __launch_bounds__(256, 4)
void k_attn(const unsigned short* __restrict__ Qh, const unsigned short* __restrict__ Kh,
            const unsigned short* __restrict__ Vt, unsigned short* __restrict__ ctx) {
  __shared__ unsigned short Kl[2 * 4096];   // [buf][slot 64][hd 64], swizzled
  __shared__ unsigned short Vl[2 * 4096];   // [buf][hd 64][kv 64],  swizzled
  // swizzled decode: xcd = bid & 7 (1024 % 8 == 0, bijective)
  const int bid = blockIdx.x;
  const int g8  = bid & 7;                  // target XCD
  const int idx = bid >> 3;                 // 0..127
  const int bh  = g8 * 8 + (idx & 7);       // 8 heads per XCD
  const int iq  = idx >> 3;                 // 0..15
  const int t = threadIdx.x, w = t >> 6, l = t & 63, lo = l & 15, hi = l >> 4;
  const unsigned short* Qb = Qh + (size_t)bh * S_ * HD_;
  const unsigned short* Kb = Kh + (size_t)bh * S_ * HD_;
  const unsigned short* Vb = Vt + (size_t)bh * S_ * HD_;   // [HD][S]
  const int bb = bh >> 4, h = bh & 15;

  // staging: 256 thr x 2 rows per matrix (rows t>>3 and +32), 16B chunks
  const int r0s = t >> 3, schunk = t & 7, r1s = r0s + 32;
  const int ks0 = ((r0s & 1) << 4) | ((r0s >> 1) & 15);            // r0s<32
  const int ks1 = 32 | ((r1s & 1) << 4) | ((r1s >> 1) & 15);
  const int kd0 = ks0 * 64 + 8 * (schunk ^ (ks0 & 7));
  const int kd1 = ks1 * 64 + 8 * (schunk ^ (ks1 & 7));
  const int vd0 = r0s * 64 + 8 * (schunk ^ (r0s & 7));
  const int vd1 = r1s * 64 + 8 * (schunk ^ (r1s & 7));
  const unsigned short* ksrc0 = Kb + r0s * HD_ + schunk * 8;          // + kv0*HD_
  const unsigned short* ksrc1 = Kb + r1s * HD_ + schunk * 8;
  const unsigned short* vsrc0 = Vb + (size_t)r0s * S_ + schunk * 8;   // + kv0
  const unsigned short* vsrc1 = Vb + (size_t)r1s * S_ + schunk * 8;

  const int q0 = iq * 128;
  const int nt = 2 * iq + 2;

  s16x8 qf[2][2];
  int qbase[2];
#pragma unroll
  for (int g = 0; g < 2; ++g) {
    qbase[g] = q0 + g * 64 + w * 16;
#pragma unroll
    for (int kk = 0; kk < 2; ++kk)
      qf[g][kk] = *(const s16x8*)(Qb + (size_t)(qbase[g] + lo) * HD_ + kk * 32 + hi * 8);
  }
  f32x4 O[2][4];
#pragma unroll
  for (int g = 0; g < 2; ++g)
#pragma unroll
    for (int nh = 0; nh < 4; ++nh) O[g][nh] = (f32x4){0.f, 0.f, 0.f, 0.f};
  float mrun[2] = {-1e30f, -1e30f}, lrun[2] = {0.f, 0.f};

  // prologue: tile 0 -> buf 0
  u16x8 rk0 = *(const u16x8*)ksrc0, rk1 = *(const u16x8*)ksrc1;
  u16x8 rv0 = *(const u16x8*)vsrc0, rv1 = *(const u16x8*)vsrc1;
  *(u16x8*)&Kl[kd0] = rk0;
  *(u16x8*)&Kl[kd1] = rk1;
  *(u16x8*)&Vl[vd0] = rv0;
  *(u16x8*)&Vl[vd1] = rv1;
  __syncthreads();

  for (int kt = 0; kt < nt; ++kt) {
    const int kv0 = kt * 64;
    const int cb = (kt & 1) * 4096;        // compute buffer
    const bool pf = (kt + 1 < nt);
    if (pf) {                              // T14: issue loads BEFORE compute
      rk0 = *(const u16x8*)(ksrc0 + (size_t)(kv0 + 64) * HD_);
      rk1 = *(const u16x8*)(ksrc1 + (size_t)(kv0 + 64) * HD_);
      rv0 = *(const u16x8*)(vsrc0 + kv0 + 64);
      rv1 = *(const u16x8*)(vsrc1 + kv0 + 64);
    }

    // S^T = K Q^T : p[g][n][r] = S[kv0+32(n>>1)+8hi+2r+(n&1)][qbase[g]+lo]
    f32x4 p[2][4];
#pragma unroll
    for (int g = 0; g < 2; ++g)
#pragma unroll
      for (int n = 0; n < 4; ++n) p[g][n] = (f32x4){0.f, 0.f, 0.f, 0.f};
#pragma unroll
    for (int kk = 0; kk < 2; ++kk) {
      s16x8 kf[4];
#pragma unroll
      for (int n = 0; n < 4; ++n)
        kf[n] = *(const s16x8*)&Kl[cb + (n * 16 + lo) * 64 + 8 * ((kk * 4 + hi) ^ (lo & 7))];
      __builtin_amdgcn_s_setprio(1);
#pragma unroll
      for (int g = 0; g < 2; ++g)
#pragma unroll
        for (int n = 0; n < 4; ++n)
          p[g][n] = __builtin_amdgcn_mfma_f32_16x16x32_bf16(kf[n], qf[g][kk], p[g][n], 0, 0, 0);
      __builtin_amdgcn_s_setprio(0);
    }

    union PU { unsigned int u[4]; s16x8 s; };
    PU pa[2][2];
#pragma unroll
    for (int g = 0; g < 2; ++g) {
      if (kv0 + 63 > qbase[g]) {           // wave-uniform: mask only diagonal tiles
        const int q = qbase[g] + lo;
#pragma unroll
        for (int n = 0; n < 4; ++n)
#pragma unroll
          for (int r = 0; r < 4; ++r) {
            int kv = kv0 + 32 * (n >> 1) + 8 * hi + 2 * r + (n & 1);
            p[g][n][r] = (kv <= q) ? p[g][n][r] : -1e30f;
          }
      }
      // row max: 15 in-lane + xor16/32 across the q-column lane group
      float mx = fmaxf(fmaxf(fmaxf(p[g][0][0], p[g][0][1]), fmaxf(p[g][0][2], p[g][0][3])),
                       fmaxf(fmaxf(p[g][1][0], p[g][1][1]), fmaxf(p[g][1][2], p[g][1][3])));
      mx = fmaxf(mx, fmaxf(fmaxf(fmaxf(p[g][2][0], p[g][2][1]), fmaxf(p[g][2][2], p[g][2][3])),
                           fmaxf(fmaxf(p[g][3][0], p[g][3][1]), fmaxf(p[g][3][2], p[g][3][3]))));
      mx = fmaxf(mx, __shfl_xor(mx, 16));
      mx = fmaxf(mx, __shfl_xor(mx, 32));
      // T13 defer-max: only rescale when max grew past THR=8 (exp2 domain)
      const bool need = !__all(mx <= mrun[g] + 8.0f);
      if (need) {
        float mnew = fmaxf(mrun[g], mx);
        float alpha = exp2f(mrun[g] - mnew);
        mrun[g] = mnew;
        lrun[g] *= alpha;
#pragma unroll
        for (int r = 0; r < 4; ++r) {
          float ar_ = __shfl(alpha, 4 * hi + r);
#pragma unroll
          for (int nh = 0; nh < 4; ++nh) O[g][nh][r] *= ar_;
        }
      }
      float sum = 0.f;
#pragma unroll
      for (int n = 0; n < 4; ++n)
#pragma unroll
        for (int r = 0; r < 4; ++r) {
          float e = exp2f(p[g][n][r] - mrun[g]);   // masked: exp2(-1e30)=0
          p[g][n][r] = e;
          sum += e;
        }
      sum += __shfl_xor(sum, 16);
      sum += __shfl_xor(sum, 32);
      lrun[g] += sum;
      // pack P -> PV A-fragment: already lane-resident, just cvt_pk pairs
#pragma unroll
      for (int c = 0; c < 2; ++c)
#pragma unroll
        for (int r = 0; r < 4; ++r) {
          unsigned int pk;
          asm("v_cvt_pk_bf16_f32 %0, %1, %2"
              : "=v"(pk) : "v"(p[g][2 * c][r]), "v"(p[g][2 * c + 1][r]));
          pa[g][c].u[r] = pk;
        }
    }

    // O += P V
#pragma unroll
    for (int c = 0; c < 2; ++c) {
      s16x8 vf[4];
#pragma unroll
      for (int nh = 0; nh < 4; ++nh)
        vf[nh] = *(const s16x8*)&Vl[cb + (nh * 16 + lo) * 64 + 8 * ((4 * c + hi) ^ (lo & 7))];
      __builtin_amdgcn_s_setprio(1);
#pragma unroll
      for (int nh = 0; nh < 4; ++nh) {
        O[0][nh] = __builtin_amdgcn_mfma_f32_16x16x32_bf16(pa[0][c].s, vf[nh], O[0][nh], 0, 0, 0);
        O[1][nh] = __builtin_amdgcn_mfma_f32_16x16x32_bf16(pa[1][c].s, vf[nh], O[1][nh], 0, 0, 0);
      }
      __builtin_amdgcn_s_setprio(0);
    }

    if (pf) {                              // T14: write next tile AFTER compute
      const int db = ((kt + 1) & 1) * 4096;
      *(u16x8*)&Kl[db + kd0] = rk0;
      *(u16x8*)&Kl[db + kd1] = rk1;
      *(u16x8*)&Vl[db + vd0] = rv0;
      *(u16x8*)&Vl[db + vd1] = rv1;
      __syncthreads();                     // one barrier per tile
    }
  }

  // epilogue: ctx[B,S,H,HD] bf16
#pragma unroll
  for (int g = 0; g < 2; ++g) {
#pragma unroll
    for (int r = 0; r < 4; ++r) {
      float li = 1.0f / __shfl(lrun[g], 4 * hi + r);
      int qg = qbase[g] + 4 * hi + r;
#pragma unroll
      for (int nh = 0; nh < 4; ++nh) {
        int hd = nh * 16 + lo;
        ctx[(((size_t)(bb * S_ + qg)) * H_ + h) * HD_ + hd] = f2bf(O[g][nh][r] * li);
      }
    }
  }
}

// ---------------------------------------------------------------- launch
extern "C" void kernel_launch(void* const* d_in, const int* in_sizes, int n_in,
                              void* d_out, int out_size, void* d_ws, size_t ws_size,
                              hipStream_t stream) {
  const float* x      = (const float*)d_in[0];
  const float* W_attn = (const float*)d_in[1];
  const float* b_attn = (const float*)d_in[2];
  const float* W_proj = (const float*)d_in[3];
  const float* b_proj = (const float*)d_in[4];
  float* out = (float*)d_out;

  char* ws = (char*)d_ws;
  size_t off = 0;
  auto alloc = [&](size_t bytes) {
    char* p = ws + off;
    off += (bytes + 255) & ~(size_t)255;
    return p;
  };
  unsigned short* xb  = (unsigned short*)alloc((size_t)8192 * 1024 * 2);
  unsigned short* Wta = (unsigned short*)alloc((size_t)3072 * 1024 * 2);
  unsigned short* Wtp = (unsigned short*)alloc((size_t)1024 * 1024 * 2);
  unsigned short* Qh  = (unsigned short*)alloc((size_t)64 * 2048 * 64 * 2);
  unsigned short* Kh  = (unsigned short*)alloc((size_t)64 * 2048 * 64 * 2);
  unsigned short* Vh  = (unsigned short*)alloc((size_t)64 * 2048 * 64 * 2);
  unsigned short* Vt  = (unsigned short*)alloc((size_t)64 * 2048 * 64 * 2);
  unsigned short* ctx = (unsigned short*)alloc((size_t)8192 * 1024 * 2);

  k_cvt<<<dim3(2048), dim3(256), 0, stream>>>(x, xb, (8192 * 1024) / 4);
  k_tpose_cvt<<<dim3(48, 16), dim3(256), 0, stream>>>(W_attn, Wta, 1024, 3072);
  k_tpose_cvt<<<dim3(16, 16), dim3(256), 0, stream>>>(W_proj, Wtp, 1024, 1024);
  k_gemm_qkv<<<dim3(24, 64), dim3(256), 0, stream>>>(xb, Wta, b_attn, Qh, Kh, Vh);
  k_tpose_v<<<dim3(32, 64), dim3(256), 0, stream>>>(Vh, Vt);
  k_attn<<<dim3(1024), dim3(256), 0, stream>>>(Qh, Kh, Vt, ctx);
  k_gemm_proj<<<dim3(8, 64), dim3(256), 0, stream>>>(ctx, Wtp, b_proj, out, 1024);
}

// Round 7
// 197.940 us; speedup vs baseline: 1.3164x; 1.3164x over previous
//
#include <hip/hip_runtime.h>
#include <hip/hip_bf16.h>
#include <stdint.h>

// Problem constants: B=4, S=2048, D=1024, H=16, HD=64
#define B_  4
#define S_  2048
#define D_  1024
#define H_  16
#define HD_ 64

typedef __attribute__((ext_vector_type(8))) short          s16x8;   // MFMA A/B frag (8 bf16)
typedef __attribute__((ext_vector_type(4))) float          f32x4;   // MFMA C/D frag
typedef __attribute__((ext_vector_type(8))) unsigned short u16x8;   // 16B bf16 chunk

__device__ __forceinline__ unsigned short f2bf(float f) {
  union { float f; unsigned int u; } v; v.f = f;
  unsigned int u = v.u;
  u += 0x7fffu + ((u >> 16) & 1u);       // RNE
  return (unsigned short)(u >> 16);
}

// async global->LDS, 16B per lane; LDS dest = wave-uniform base + lane*16
#define GLDS16(g, l)                                                           \
  __builtin_amdgcn_global_load_lds(                                            \
      (const __attribute__((address_space(1))) void*)(g),                      \
      (__attribute__((address_space(3))) void*)(l), 16, 0, 0)

// ---------------------------------------------------------------- converts
__global__ void k_cvt(const float* __restrict__ src, unsigned short* __restrict__ dst, int n4) {
  int i = blockIdx.x * blockDim.x + threadIdx.x;
  int stride = gridDim.x * blockDim.x;
  for (int j = i; j < n4; j += stride) {
    float4 v = reinterpret_cast<const float4*>(src)[j];
    ushort4 o;
    o.x = f2bf(v.x); o.y = f2bf(v.y); o.z = f2bf(v.z); o.w = f2bf(v.w);
    reinterpret_cast<ushort4*>(dst)[j] = o;
  }
}

// fp32 [R][C] -> bf16 [C][R]   (weights -> B^T layout for gemm-BT)
__global__ void k_tpose_cvt(const float* __restrict__ src, unsigned short* __restrict__ dst,
                            int R, int C) {
  __shared__ unsigned short tile[64][72];
  int c0 = blockIdx.x * 64, r0 = blockIdx.y * 64;
  int tx = threadIdx.x & 63, ty = threadIdx.x >> 6;
#pragma unroll
  for (int i = 0; i < 16; ++i) {
    int r = ty * 16 + i;
    tile[r][tx] = f2bf(src[(size_t)(r0 + r) * C + c0 + tx]);
  }
  __syncthreads();
#pragma unroll
  for (int i = 0; i < 16; ++i) {
    int c = ty * 16 + i;
    dst[(size_t)(c0 + c) * R + r0 + tx] = tile[tx][c];
  }
}

// bf16 V [BH][S][HD] -> Vt [BH][HD][S]
__global__ void k_tpose_v(const unsigned short* __restrict__ src, unsigned short* __restrict__ dst) {
  __shared__ unsigned short tile[64][72];
  int s0 = blockIdx.x * 64, bh = blockIdx.y;
  int tx = threadIdx.x & 63, ty = threadIdx.x >> 6;
  const unsigned short* sb = src + (size_t)bh * S_ * HD_;
  unsigned short*       db = dst + (size_t)bh * S_ * HD_;
#pragma unroll
  for (int i = 0; i < 16; ++i) {
    int r = ty * 16 + i;
    tile[r][tx] = sb[(size_t)(s0 + r) * HD_ + tx];
  }
  __syncthreads();
#pragma unroll
  for (int i = 0; i < 16; ++i) {
    int hd = ty * 16 + i;
    db[(size_t)hd * S_ + s0 + tx] = tile[tx][hd];
  }
}

// ---------------------------------------------------------------- GEMM core
// C[128x128] = A[M,K] @ Bt[N,K]^T ; bf16 in, f32 acc; 4 waves (2x2), wave
// tile 64x64 = 4x4 frags of mfma_f32_16x16x32_bf16.
// Staging: global_load_lds width=16, LINEAR LDS dest (m104 rule), XOR chunk
// swizzle applied to the GLOBAL source address (same involution the reads
// use). One barrier per K-step.
__device__ __forceinline__ void gemm_core(const unsigned short* __restrict__ A,
                                          const unsigned short* __restrict__ Bt,
                                          int K, int m0, int n0,
                                          unsigned short* sm, f32x4 acc[4][4]) {
  const int t = threadIdx.x;
  const int w = t >> 6, l = t & 63;
  const int wm = w >> 1, wn = w & 1;
  const int lo = l & 15, hi = l >> 4;

  // chunk ci = j*256 + w*64 + l  (j=0,1); row = ci>>2; source chunk pre-swizzled
  const int ci0 = w * 64 + l, ci1 = ci0 + 256;
  const int rA0 = ci0 >> 2, cA0 = (ci0 & 3) ^ ((rA0 >> 1) & 3);
  const int rA1 = ci1 >> 2, cA1 = (ci1 & 3) ^ ((rA1 >> 1) & 3);
  const unsigned short* gA0 = A  + (size_t)(m0 + rA0) * K + cA0 * 8;
  const unsigned short* gA1 = A  + (size_t)(m0 + rA1) * K + cA1 * 8;
  const unsigned short* gB0 = Bt + (size_t)(n0 + rA0) * K + cA0 * 8;
  const unsigned short* gB1 = Bt + (size_t)(n0 + rA1) * K + cA1 * 8;
  const int ldsA0 = (w * 64) * 8;          // wave-uniform LDS bases (shorts)
  const int ldsA1 = (256 + w * 64) * 8;

#pragma unroll
  for (int m = 0; m < 4; ++m)
#pragma unroll
    for (int n = 0; n < 4; ++n)
      acc[m][n] = (f32x4){0.f, 0.f, 0.f, 0.f};

  const int NT = K >> 5;  // BK = 32

  // prologue: tile 0 -> buf 0
  {
    unsigned short* b = sm;
    GLDS16(gA0, b + ldsA0);
    GLDS16(gA1, b + ldsA1);
    GLDS16(gB0, b + 4096 + ldsA0);
    GLDS16(gB1, b + 4096 + ldsA1);
  }

  for (int kt = 0; kt < NT; ++kt) {
    __syncthreads();   // vmcnt(0)+lgkmcnt(0) drain: buf[kt&1] staged, prev reads done
    if (kt + 1 < NT) {                       // issue next tile into other buffer
      unsigned short* b = sm + ((kt + 1) & 1) * 8192;
      const int ko = (kt + 1) << 5;
      GLDS16(gA0 + ko, b + ldsA0);
      GLDS16(gA1 + ko, b + ldsA1);
      GLDS16(gB0 + ko, b + 4096 + ldsA0);
      GLDS16(gB1 + ko, b + 4096 + ldsA1);
    }
    const unsigned short* Ab = sm + (kt & 1) * 8192;
    const unsigned short* Bb = Ab + 4096;
    s16x8 af[4], bfr[4];
#pragma unroll
    for (int m = 0; m < 4; ++m) {
      int row = wm * 64 + m * 16 + lo;
      af[m] = *(const s16x8*)(Ab + row * 32 + ((hi ^ ((row >> 1) & 3)) << 3));
    }
#pragma unroll
    for (int n = 0; n < 4; ++n) {
      int row = wn * 64 + n * 16 + lo;
      bfr[n] = *(const s16x8*)(Bb + row * 32 + ((hi ^ ((row >> 1) & 3)) << 3));
    }
    __builtin_amdgcn_s_setprio(1);
#pragma unroll
    for (int m = 0; m < 4; ++m)
#pragma unroll
      for (int n = 0; n < 4; ++n)
        acc[m][n] = __builtin_amdgcn_mfma_f32_16x16x32_bf16(af[m], bfr[n], acc[m][n], 0, 0, 0);
    __builtin_amdgcn_s_setprio(0);
  }
}

// GEMM1: qkv = x @ W_attn + b ; scatter into Q/K/V [B,H,S,HD] bf16.
// Q is pre-scaled by 0.125*log2(e) so attention runs in exp2 domain.
__global__ __launch_bounds__(256, 3)
void k_gemm_qkv(const unsigned short* __restrict__ A, const unsigned short* __restrict__ Bt,
                const float* __restrict__ bias,
                unsigned short* __restrict__ Qh, unsigned short* __restrict__ Kh,
                unsigned short* __restrict__ Vh) {
  __shared__ unsigned short sm[2 * 8192];
  const int m0 = blockIdx.y * 128, n0 = blockIdx.x * 128;
  f32x4 acc[4][4];
  gemm_core(A, Bt, 1024, m0, n0, sm, acc);
  const int t = threadIdx.x, w = t >> 6, l = t & 63;
  const int wm = w >> 1, wn = w & 1, lo = l & 15, hi = l >> 4;
#pragma unroll
  for (int m = 0; m < 4; ++m)
#pragma unroll
    for (int n = 0; n < 4; ++n) {
      int col = n0 + wn * 64 + n * 16 + lo;           // 0..3071
      float bv = bias[col];
      int sel = col >> 10, cw = col & 1023, h = cw >> 6, hd = cw & 63;
      float scl = (sel == 0) ? 0.18033688011112042f : 1.0f;  // log2(e)/8
      unsigned short* dst = (sel == 0) ? Qh : ((sel == 1) ? Kh : Vh);
#pragma unroll
      for (int r = 0; r < 4; ++r) {
        int row = m0 + wm * 64 + m * 16 + hi * 4 + r;
        int b = row >> 11, s = row & 2047;
        dst[(((size_t)b * H_ + h) * S_ + s) * HD_ + hd] = f2bf((acc[m][n][r] + bv) * scl);
      }
    }
}

// GEMM2: out = ctx @ W_proj + b ; fp32 out
__global__ __launch_bounds__(256, 3)
void k_gemm_proj(const unsigned short* __restrict__ A, const unsigned short* __restrict__ Bt,
                 const float* __restrict__ bias, float* __restrict__ C, int N) {
  __shared__ unsigned short sm[2 * 8192];
  const int m0 = blockIdx.y * 128, n0 = blockIdx.x * 128;
  f32x4 acc[4][4];
  gemm_core(A, Bt, 1024, m0, n0, sm, acc);
  const int t = threadIdx.x, w = t >> 6, l = t & 63;
  const int wm = w >> 1, wn = w & 1, lo = l & 15, hi = l >> 4;
#pragma unroll
  for (int m = 0; m < 4; ++m)
#pragma unroll
    for (int n = 0; n < 4; ++n) {
      int col = n0 + wn * 64 + n * 16 + lo;
      float bv = bias[col];
#pragma unroll
      for (int r = 0; r < 4; ++r) {
        int row = m0 + wm * 64 + m * 16 + hi * 4 + r;
        C[(size_t)row * N + col] = acc[m][n][r] + bv;
      }
    }
}

// ---------------------------------------------------------------- attention
// Swapped QK^T (mfma(K,Q)); K rows LDS-permuted so the PV A-fragment is
// lane-resident after cvt_pk (zero shuffles for P); G4 XOR chunk swizzle on
// K/V (0 bank conflicts). T13 defer-max (THR=8, exp2 domain).
// Structure (round 6, verified correct): 256-thread blocks, one q-tile,
// 1024 blocks; double-buffered K/V LDS + T14 async-STAGE split (one barrier
// per KV tile); XCD swizzle puts all 16 q-tiles of 8 heads on one XCD ->
// 4MB L2-resident K/V (FETCH 110->49 MB measured).
// Round-7 fix: launch_bounds (256,2). Rounds 4/6 used min-waves=4 which caps
// the UNIFIED VGPR+AGPR file at 128/wave; MFMA accumulators take ~64 so the
// kernel spilled (VGPR_Count=64, WRITE_SIZE 282 MB). Cap 256 -> natural
// ~110-125 regs, no spill; runtime occupancy set by usage (<=128 -> 4/CU).
__global__ __launch_bounds__(256, 2)
void k_attn(const unsigned short* __restrict__ Qh, const unsigned short* __restrict__ Kh,
            const unsigned short* __restrict__ Vt, unsigned short* __restrict__ ctx) {
  __shared__ unsigned short Kl[2 * 4096];   // [buf][slot 64][hd 64], swizzled
  __shared__ unsigned short Vl[2 * 4096];   // [buf][hd 64][kv 64],  swizzled
  // swizzled decode: xcd = bid & 7 (1024 % 8 == 0, bijective)
  const int bid = blockIdx.x;
  const int g8  = bid & 7;                  // target XCD
  const int idx = bid >> 3;                 // 0..127
  const int bh  = g8 * 8 + (idx & 7);       // 8 heads per XCD
  const int iq  = idx >> 3;                 // 0..15
  const int t = threadIdx.x, w = t >> 6, l = t & 63, lo = l & 15, hi = l >> 4;
  const unsigned short* Qb = Qh + (size_t)bh * S_ * HD_;
  const unsigned short* Kb = Kh + (size_t)bh * S_ * HD_;
  const unsigned short* Vb = Vt + (size_t)bh * S_ * HD_;   // [HD][S]
  const int bb = bh >> 4, h = bh & 15;

  // staging: 256 thr x 2 rows per matrix (rows t>>3 and +32), 16B chunks
  const int r0s = t >> 3, schunk = t & 7, r1s = r0s + 32;
  const int ks0 = ((r0s & 1) << 4) | ((r0s >> 1) & 15);            // r0s<32
  const int ks1 = 32 | ((r1s & 1) << 4) | ((r1s >> 1) & 15);
  const int kd0 = ks0 * 64 + 8 * (schunk ^ (ks0 & 7));
  const int kd1 = ks1 * 64 + 8 * (schunk ^ (ks1 & 7));
  const int vd0 = r0s * 64 + 8 * (schunk ^ (r0s & 7));
  const int vd1 = r1s * 64 + 8 * (schunk ^ (r1s & 7));
  const unsigned short* ksrc0 = Kb + r0s * HD_ + schunk * 8;          // + kv0*HD_
  const unsigned short* ksrc1 = Kb + r1s * HD_ + schunk * 8;
  const unsigned short* vsrc0 = Vb + (size_t)r0s * S_ + schunk * 8;   // + kv0
  const unsigned short* vsrc1 = Vb + (size_t)r1s * S_ + schunk * 8;

  const int q0 = iq * 128;
  const int nt = 2 * iq + 2;

  s16x8 qf[2][2];
  int qbase[2];
#pragma unroll
  for (int g = 0; g < 2; ++g) {
    qbase[g] = q0 + g * 64 + w * 16;
#pragma unroll
    for (int kk = 0; kk < 2; ++kk)
      qf[g][kk] = *(const s16x8*)(Qb + (size_t)(qbase[g] + lo) * HD_ + kk * 32 + hi * 8);
  }
  f32x4 O[2][4];
#pragma unroll
  for (int g = 0; g < 2; ++g)
#pragma unroll
    for (int nh = 0; nh < 4; ++nh) O[g][nh] = (f32x4){0.f, 0.f, 0.f, 0.f};
  float mrun[2] = {-1e30f, -1e30f}, lrun[2] = {0.f, 0.f};

  // prologue: tile 0 -> buf 0
  u16x8 rk0 = *(const u16x8*)ksrc0, rk1 = *(const u16x8*)ksrc1;
  u16x8 rv0 = *(const u16x8*)vsrc0, rv1 = *(const u16x8*)vsrc1;
  *(u16x8*)&Kl[kd0] = rk0;
  *(u16x8*)&Kl[kd1] = rk1;
  *(u16x8*)&Vl[vd0] = rv0;
  *(u16x8*)&Vl[vd1] = rv1;
  __syncthreads();

  for (int kt = 0; kt < nt; ++kt) {
    const int kv0 = kt * 64;
    const int cb = (kt & 1) * 4096;        // compute buffer
    const bool pf = (kt + 1 < nt);
    if (pf) {                              // T14: issue loads BEFORE compute
      rk0 = *(const u16x8*)(ksrc0 + (size_t)(kv0 + 64) * HD_);
      rk1 = *(const u16x8*)(ksrc1 + (size_t)(kv0 + 64) * HD_);
      rv0 = *(const u16x8*)(vsrc0 + kv0 + 64);
      rv1 = *(const u16x8*)(vsrc1 + kv0 + 64);
    }

    // S^T = K Q^T : p[g][n][r] = S[kv0+32(n>>1)+8hi+2r+(n&1)][qbase[g]+lo]
    f32x4 p[2][4];
#pragma unroll
    for (int g = 0; g < 2; ++g)
#pragma unroll
      for (int n = 0; n < 4; ++n) p[g][n] = (f32x4){0.f, 0.f, 0.f, 0.f};
#pragma unroll
    for (int kk = 0; kk < 2; ++kk) {
      s16x8 kf[4];
#pragma unroll
      for (int n = 0; n < 4; ++n)
        kf[n] = *(const s16x8*)&Kl[cb + (n * 16 + lo) * 64 + 8 * ((kk * 4 + hi) ^ (lo & 7))];
      __builtin_amdgcn_s_setprio(1);
#pragma unroll
      for (int g = 0; g < 2; ++g)
#pragma unroll
        for (int n = 0; n < 4; ++n)
          p[g][n] = __builtin_amdgcn_mfma_f32_16x16x32_bf16(kf[n], qf[g][kk], p[g][n], 0, 0, 0);
      __builtin_amdgcn_s_setprio(0);
    }

    union PU { unsigned int u[4]; s16x8 s; };
    PU pa[2][2];
#pragma unroll
    for (int g = 0; g < 2; ++g) {
      if (kv0 + 63 > qbase[g]) {           // wave-uniform: mask only diagonal tiles
        const int q = qbase[g] + lo;
#pragma unroll
        for (int n = 0; n < 4; ++n)
#pragma unroll
          for (int r = 0; r < 4; ++r) {
            int kv = kv0 + 32 * (n >> 1) + 8 * hi + 2 * r + (n & 1);
            p[g][n][r] = (kv <= q) ? p[g][n][r] : -1e30f;
          }
      }
      // row max: 15 in-lane + xor16/32 across the q-column lane group
      float mx = fmaxf(fmaxf(fmaxf(p[g][0][0], p[g][0][1]), fmaxf(p[g][0][2], p[g][0][3])),
                       fmaxf(fmaxf(p[g][1][0], p[g][1][1]), fmaxf(p[g][1][2], p[g][1][3])));
      mx = fmaxf(mx, fmaxf(fmaxf(fmaxf(p[g][2][0], p[g][2][1]), fmaxf(p[g][2][2], p[g][2][3])),
                           fmaxf(fmaxf(p[g][3][0], p[g][3][1]), fmaxf(p[g][3][2], p[g][3][3]))));
      mx = fmaxf(mx, __shfl_xor(mx, 16));
      mx = fmaxf(mx, __shfl_xor(mx, 32));
      // T13 defer-max: only rescale when max grew past THR=8 (exp2 domain)
      const bool need = !__all(mx <= mrun[g] + 8.0f);
      if (need) {
        float mnew = fmaxf(mrun[g], mx);
        float alpha = exp2f(mrun[g] - mnew);
        mrun[g] = mnew;
        lrun[g] *= alpha;
#pragma unroll
        for (int r = 0; r < 4; ++r) {
          float ar_ = __shfl(alpha, 4 * hi + r);
#pragma unroll
          for (int nh = 0; nh < 4; ++nh) O[g][nh][r] *= ar_;
        }
      }
      float sum = 0.f;
#pragma unroll
      for (int n = 0; n < 4; ++n)
#pragma unroll
        for (int r = 0; r < 4; ++r) {
          float e = exp2f(p[g][n][r] - mrun[g]);   // masked: exp2(-1e30)=0
          p[g][n][r] = e;
          sum += e;
        }
      sum += __shfl_xor(sum, 16);
      sum += __shfl_xor(sum, 32);
      lrun[g] += sum;
      // pack P -> PV A-fragment: already lane-resident, just cvt_pk pairs
#pragma unroll
      for (int c = 0; c < 2; ++c)
#pragma unroll
        for (int r = 0; r < 4; ++r) {
          unsigned int pk;
          asm("v_cvt_pk_bf16_f32 %0, %1, %2"
              : "=v"(pk) : "v"(p[g][2 * c][r]), "v"(p[g][2 * c + 1][r]));
          pa[g][c].u[r] = pk;
        }
    }

    // O += P V
#pragma unroll
    for (int c = 0; c < 2; ++c) {
      s16x8 vf[4];
#pragma unroll
      for (int nh = 0; nh < 4; ++nh)
        vf[nh] = *(const s16x8*)&Vl[cb + (nh * 16 + lo) * 64 + 8 * ((4 * c + hi) ^ (lo & 7))];
      __builtin_amdgcn_s_setprio(1);
#pragma unroll
      for (int nh = 0; nh < 4; ++nh) {
        O[0][nh] = __builtin_amdgcn_mfma_f32_16x16x32_bf16(pa[0][c].s, vf[nh], O[0][nh], 0, 0, 0);
        O[1][nh] = __builtin_amdgcn_mfma_f32_16x16x32_bf16(pa[1][c].s, vf[nh], O[1][nh], 0, 0, 0);
      }
      __builtin_amdgcn_s_setprio(0);
    }

    if (pf) {                              // T14: write next tile AFTER compute
      const int db = ((kt + 1) & 1) * 4096;
      *(u16x8*)&Kl[db + kd0] = rk0;
      *(u16x8*)&Kl[db + kd1] = rk1;
      *(u16x8*)&Vl[db + vd0] = rv0;
      *(u16x8*)&Vl[db + vd1] = rv1;
      __syncthreads();                     // one barrier per tile
    }
  }

  // epilogue: ctx[B,S,H,HD] bf16
#pragma unroll
  for (int g = 0; g < 2; ++g) {
#pragma unroll
    for (int r = 0; r < 4; ++r) {
      float li = 1.0f / __shfl(lrun[g], 4 * hi + r);
      int qg = qbase[g] + 4 * hi + r;
#pragma unroll
      for (int nh = 0; nh < 4; ++nh) {
        int hd = nh * 16 + lo;
        ctx[(((size_t)(bb * S_ + qg)) * H_ + h) * HD_ + hd] = f2bf(O[g][nh][r] * li);
      }
    }
  }
}

// ---------------------------------------------------------------- launch
extern "C" void kernel_launch(void* const* d_in, const int* in_sizes, int n_in,
                              void* d_out, int out_size, void* d_ws, size_t ws_size,
                              hipStream_t stream) {
  const float* x      = (const float*)d_in[0];
  const float* W_attn = (const float*)d_in[1];
  const float* b_attn = (const float*)d_in[2];
  const float* W_proj = (const float*)d_in[3];
  const float* b_proj = (const float*)d_in[4];
  float* out = (float*)d_out;

  char* ws = (char*)d_ws;
  size_t off = 0;
  auto alloc = [&](size_t bytes) {
    char* p = ws + off;
    off += (bytes + 255) & ~(size_t)255;
    return p;
  };
  unsigned short* xb  = (unsigned short*)alloc((size_t)8192 * 1024 * 2);
  unsigned short* Wta = (unsigned short*)alloc((size_t)3072 * 1024 * 2);
  unsigned short* Wtp = (unsigned short*)alloc((size_t)1024 * 1024 * 2);
  unsigned short* Qh  = (unsigned short*)alloc((size_t)64 * 2048 * 64 * 2);
  unsigned short* Kh  = (unsigned short*)alloc((size_t)64 * 2048 * 64 * 2);
  unsigned short* Vh  = (unsigned short*)alloc((size_t)64 * 2048 * 64 * 2);
  unsigned short* Vt  = (unsigned short*)alloc((size_t)64 * 2048 * 64 * 2);
  unsigned short* ctx = (unsigned short*)alloc((size_t)8192 * 1024 * 2);

  k_cvt<<<dim3(2048), dim3(256), 0, stream>>>(x, xb, (8192 * 1024) / 4);
  k_tpose_cvt<<<dim3(48, 16), dim3(256), 0, stream>>>(W_attn, Wta, 1024, 3072);
  k_tpose_cvt<<<dim3(16, 16), dim3(256), 0, stream>>>(W_proj, Wtp, 1024, 1024);
  k_gemm_qkv<<<dim3(24, 64), dim3(256), 0, stream>>>(xb, Wta, b_attn, Qh, Kh, Vh);
  k_tpose_v<<<dim3(32, 64), dim3(256), 0, stream>>>(Vh, Vt);
  k_attn<<<dim3(1024), dim3(256), 0, stream>>>(Qh, Kh, Vt, ctx);
  k_gemm_proj<<<dim3(8, 64), dim3(256), 0, stream>>>(ctx, Wtp, b_proj, out, 1024);
}